// Round 8
// baseline (757.006 us; speedup 1.0000x reference)
//
#include <hip/hip_runtime.h>
#include <hip/hip_bf16.h>

#define N_NODES 100000
#define N_EDGES 1600000
#define IN_F 128
#define C1 64      // HEADS*HID
#define NC 16      // classes / layer2 width

#define GEMM1_NB (N_NODES / 16)          // 6250
#define EDGE_NB (N_EDGES / 256)          // 6250: 4 waves/block, 64 edges/wave

__device__ __forceinline__ float lrelu(float x) { return fmaxf(x, 0.2f * x); }

// ---------------- layer 1 GEMM + attention dots + self-loop seed ------------
// 16 nodes/block; thread t: node_l=t>>4, cols cq=(t&15)*4..+3, head h=cq/16.
__global__ __launch_bounds__(256) void k_gemm1(
    const float* __restrict__ x, const float* __restrict__ W1,
    const float* __restrict__ att_src1, const float* __restrict__ att_dst1,
    float* __restrict__ h1, float* __restrict__ a_src1, float* __restrict__ a_dst1,
    float* __restrict__ num1, float* __restrict__ den1) {
    __shared__ __align__(16) float wS[64 * C1];     // 16 KB, one k-half of W1
    __shared__ __align__(16) float xS[16 * 132];    // stride 132: aligned + conflict-free
    __shared__ float aSs[C1], aSd[C1];
    int tid = threadIdx.x;
    int node0 = blockIdx.x * 16;
    for (int i = tid; i < (16 * IN_F) / 4; i += 256) {
        int r = i >> 5, c4 = (i & 31) << 2;          // 32 float4 per 128-wide row
        *(float4*)&xS[r * 132 + c4] = *(const float4*)&x[(node0 + r) * IN_F + c4];
    }
    if (tid < C1) { aSs[tid] = att_src1[tid]; aSd[tid] = att_dst1[tid]; }

    int node_l = tid >> 4;
    int cq = (tid & 15) << 2;
    const float* xrow = &xS[node_l * 132];
    float4 acc = {0.f, 0.f, 0.f, 0.f};
#pragma unroll
    for (int kt = 0; kt < 2; kt++) {                // two 64-wide k-tiles of W1
        __syncthreads();                            // protect wS reuse
        for (int i = tid; i < (64 * C1) / 4; i += 256)
            *(float4*)&wS[i * 4] = *(const float4*)&W1[kt * 64 * C1 + i * 4];
        __syncthreads();
        const float* xk = xrow + kt * 64;
#pragma unroll 4
        for (int k = 0; k < 64; k++) {
            float xv = xk[k];
            float4 wv = *(const float4*)&wS[k * C1 + cq];
            acc.x += xv * wv.x; acc.y += xv * wv.y; acc.z += xv * wv.z; acc.w += xv * wv.w;
        }
    }
    int node = node0 + node_l;
    *(float4*)&h1[node * C1 + cq] = acc;

    float ps = acc.x * aSs[cq] + acc.y * aSs[cq + 1] + acc.z * aSs[cq + 2] + acc.w * aSs[cq + 3];
    float pd = acc.x * aSd[cq] + acc.y * aSd[cq + 1] + acc.z * aSd[cq + 2] + acc.w * aSd[cq + 3];
    ps += __shfl_xor(ps, 1); ps += __shfl_xor(ps, 2);   // 4-lane quad = one head
    pd += __shfl_xor(pd, 1); pd += __shfl_xor(pd, 2);

    float w0 = __expf(lrelu(ps + pd));              // self-loop weight (no shift)
    float4 seed = {w0 * acc.x, w0 * acc.y, w0 * acc.z, w0 * acc.w};
    *(float4*)&num1[node * C1 + cq] = seed;         // seed accumulators: no memset
    if ((tid & 3) == 0) {
        int h = (tid & 15) >> 2;
        a_src1[node * 4 + h] = ps;
        a_dst1[node * 4 + h] = pd;
        den1[node * 4 + h] = w0;
    }
}

// ---------------- layer 1 edge-parallel softmax-weighted scatter ------------
// one wave per 64 edges; all 64 lanes on one edge (lane = col).
__global__ __launch_bounds__(256) void k_edge1(
    const int* __restrict__ e_src, const int* __restrict__ e_dst,
    const float* __restrict__ h1, const float* __restrict__ a_src1,
    const float* __restrict__ a_dst1, float* __restrict__ num1,
    float* __restrict__ den1) {
    int lane = threadIdx.x & 63;
    int e0 = ((blockIdx.x * 256 + threadIdx.x) >> 6) * 64;
    int h = lane >> 4;
    int s_l = e_src[e0 + lane];                     // coalesced edge preload
    int d_l = e_dst[e0 + lane];
#pragma unroll 4
    for (int j = 0; j < 64; j++) {
        int s = __shfl(s_l, j);
        int d = __shfl(d_l, j);
        float w = __expf(lrelu(a_src1[s * 4 + h] + a_dst1[d * 4 + h]));
        float val = w * h1[s * C1 + lane];          // coalesced 256B gather
        atomicAdd(&num1[d * C1 + lane], val);       // coalesced 256B atomic
        if ((lane & 15) == 0) atomicAdd(&den1[d * 4 + h], w);
    }
}

// ---------------- layer 1 normalize + bias + ELU -> embeddings --------------
__global__ __launch_bounds__(256) void k_norm1(
    const float* __restrict__ num1, const float* __restrict__ den1,
    const float* __restrict__ b1, float* __restrict__ out_emb) {
    int i = blockIdx.x * 256 + threadIdx.x;         // N*16 quads
    int node = i >> 4, q = i & 15, h = q >> 2;
    float4 v = *(const float4*)&num1[node * C1 + q * 4];
    float4 b = *(const float4*)&b1[q * 4];
    float dn = den1[node * 4 + h];
    float4 o;
    o.x = v.x / dn + b.x; o.y = v.y / dn + b.y;
    o.z = v.z / dn + b.z; o.w = v.w / dn + b.w;
    o.x = (o.x > 0.f) ? o.x : expm1f(o.x);
    o.y = (o.y > 0.f) ? o.y : expm1f(o.y);
    o.z = (o.z > 0.f) ? o.z : expm1f(o.z);
    o.w = (o.w > 0.f) ? o.w : expm1f(o.w);
    *(float4*)&out_emb[node * C1 + q * 4] = o;      // fp32 embeddings == h_act
}

// ---------------- layer 2 GEMM + attention dots + self-loop seed ------------
__global__ __launch_bounds__(256) void k_gemm2(
    const float* __restrict__ h_act, const float* __restrict__ W2,
    const float* __restrict__ att_src2, const float* __restrict__ att_dst2,
    float* __restrict__ h2, float* __restrict__ a_src2, float* __restrict__ a_dst2,
    float* __restrict__ num2, float* __restrict__ den2) {
    __shared__ float wS[C1 * NC];                 // 4 KB [k][c]
    __shared__ __align__(16) float hS[16 * 68];   // stride 68: aligned + conflict-free
    __shared__ float aS[NC], aD[NC];
    int tid = threadIdx.x;
    int node0 = blockIdx.x * 16;
    if (tid < (C1 * NC) / 4)
        *(float4*)&wS[tid * 4] = *(const float4*)&W2[tid * 4];
    {   // 16 rows x 64 cols of h_act, 256 float4s
        int r = tid >> 4, c4 = (tid & 15) << 2;
        *(float4*)&hS[r * 68 + c4] = *(const float4*)&h_act[(node0 + r) * C1 + c4];
    }
    if (tid < NC) { aS[tid] = att_src2[tid]; aD[tid] = att_dst2[tid]; }
    __syncthreads();

    int node_l = tid >> 4, c = tid & 15;
    const float* hr = &hS[node_l * 68];
    float acc = 0.f;
#pragma unroll 8
    for (int k = 0; k < C1; k++) acc += hr[k] * wS[k * NC + c];
    int node = node0 + node_l;
    h2[node * NC + c] = acc;

    float ps = acc * aS[c], pd = acc * aD[c];
    for (int off = 8; off; off >>= 1) { ps += __shfl_xor(ps, off); pd += __shfl_xor(pd, off); }
    float w0 = __expf(lrelu(ps + pd));              // self-loop weight
    num2[node * NC + c] = w0 * acc;                 // seed accumulators
    if (c == 0) { a_src2[node] = ps; a_dst2[node] = pd; den2[node] = w0; }
}

// ---------------- layer 2 edge-parallel scatter (4 edges x 16 cols / wave) --
__global__ __launch_bounds__(256) void k_edge2(
    const int* __restrict__ e_src, const int* __restrict__ e_dst,
    const float* __restrict__ h2, const float* __restrict__ a_src2,
    const float* __restrict__ a_dst2, float* __restrict__ num2,
    float* __restrict__ den2) {
    int lane = threadIdx.x & 63;
    int e0 = ((blockIdx.x * 256 + threadIdx.x) >> 6) * 64;
    int esub = lane >> 4, c = lane & 15;
    int s_l = e_src[e0 + lane];                     // coalesced edge preload
    int d_l = e_dst[e0 + lane];
#pragma unroll 4
    for (int j2 = 0; j2 < 64; j2 += 4) {
        int jj = j2 + esub;
        int s = __shfl(s_l, jj);
        int d = __shfl(d_l, jj);
        float w = __expf(lrelu(a_src2[s] + a_dst2[d]));
        atomicAdd(&num2[d * NC + c], w * h2[s * NC + c]);
        if (c == 0) atomicAdd(&den2[d], w);
    }
}

// ---------------- layer 2 normalize + bias + log_softmax --------------------
__global__ __launch_bounds__(256) void k_norm2(
    const float* __restrict__ num2, const float* __restrict__ den2,
    const float* __restrict__ b2, float* __restrict__ out_lsm) {
    int tid = threadIdx.x;
    int node = blockIdx.x * 16 + (tid >> 4);
    int c = tid & 15;
    float logit = num2[node * NC + c] / den2[node] + b2[c];
    float mxl = logit;
    for (int off = 8; off; off >>= 1) mxl = fmaxf(mxl, __shfl_xor(mxl, off));
    float ex = __expf(logit - mxl);
    float se = ex;
    for (int off = 8; off; off >>= 1) se += __shfl_xor(se, off);
    out_lsm[node * NC + c] = (logit - mxl) - __logf(se);
}

extern "C" void kernel_launch(void* const* d_in, const int* in_sizes, int n_in,
                              void* d_out, int out_size, void* d_ws, size_t ws_size,
                              hipStream_t stream) {
    const float* x   = (const float*)d_in[0];
    const int* ei    = (const int*)d_in[1];   // [2,E]: src row then dst row
    const float* W1  = (const float*)d_in[2];
    const float* as1 = (const float*)d_in[3];
    const float* ad1 = (const float*)d_in[4];
    const float* b1  = (const float*)d_in[5];
    const float* W2  = (const float*)d_in[6];
    const float* as2 = (const float*)d_in[7];
    const float* ad2 = (const float*)d_in[8];
    const float* b2  = (const float*)d_in[9];
    float* out = (float*)d_out;               // [N*16 log_softmax][N*64 embeddings]
    float* out_lsm = out;
    float* out_emb = out + (size_t)N_NODES * NC;

    float* ws = (float*)d_ws;
    float* h1     = ws;                              // N*64
    float* a_src1 = h1     + (size_t)N_NODES * C1;   // N*4
    float* a_dst1 = a_src1 + (size_t)N_NODES * 4;    // N*4
    float* num1   = a_dst1 + (size_t)N_NODES * 4;    // N*64
    float* den1   = num1   + (size_t)N_NODES * C1;   // N*4
    float* h2     = den1   + (size_t)N_NODES * 4;    // N*16
    float* a_src2 = h2     + (size_t)N_NODES * NC;   // N
    float* a_dst2 = a_src2 + (size_t)N_NODES;        // N
    float* num2   = a_dst2 + (size_t)N_NODES;        // N*16
    float* den2   = num2   + (size_t)N_NODES * NC;   // N
    // total ws use: ~70 MB; no memsets needed (gemm kernels seed num/den)

    const int* e_src = ei;
    const int* e_dst = ei + N_EDGES;

    k_gemm1<<<GEMM1_NB, 256, 0, stream>>>(x, W1, as1, ad1, h1, a_src1, a_dst1, num1, den1);
    k_edge1<<<EDGE_NB, 256, 0, stream>>>(e_src, e_dst, h1, a_src1, a_dst1, num1, den1);
    k_norm1<<<(N_NODES * 16) / 256, 256, 0, stream>>>(num1, den1, b1, out_emb);
    k_gemm2<<<N_NODES / 16, 256, 0, stream>>>(out_emb, W2, as2, ad2, h2, a_src2, a_dst2, num2, den2);
    k_edge2<<<EDGE_NB, 256, 0, stream>>>(e_src, e_dst, h2, a_src2, a_dst2, num2, den2);
    k_norm2<<<N_NODES / 16, 256, 0, stream>>>(num2, den2, b2, out_lsm);
}

// Round 10
// 450.064 us; speedup vs baseline: 1.6820x; 1.6820x over previous
//
#include <hip/hip_runtime.h>
#include <hip/hip_bf16.h>

#define N_NODES 100000
#define N_EDGES 1600000
#define IN_F 128
#define C1 64      // HEADS*HID
#define NC 16      // classes / layer2 width

#define SCAN_TILE 1024
#define SCAN_NB ((N_NODES + SCAN_TILE - 1) / SCAN_TILE)   // 98 blocks
#define GEMM1_NB (N_NODES / 16)                           // 6250
#define HIST_NB ((N_EDGES + 1023) / 1024)                 // 1563 (4 edges/thread)

__device__ __forceinline__ float lrelu(float x) { return fmaxf(x, 0.2f * x); }
__device__ __forceinline__ float selh(float4 v, int h) {
    return (h == 0) ? v.x : (h == 1) ? v.y : (h == 2) ? v.z : v.w;
}

// ---------------- fused: histogram+rank (mem-latency-bound) + layer1 GEMM ----
// hist blocks first; gemm1 blocks after. ~25KB LDS -> 6 blocks/CU keeps the
// hist blocks at high occupancy.
__global__ __launch_bounds__(256) void k_hist_gemm1(
    const int* __restrict__ e_dst, int* __restrict__ deg, int* __restrict__ rank,
    const float* __restrict__ x, const float* __restrict__ W1,
    const float* __restrict__ att_src1, const float* __restrict__ att_dst1,
    float* __restrict__ h1, float* __restrict__ a_src1, float* __restrict__ a_dst1) {
    __shared__ __align__(16) float wS[64 * C1];     // 16 KB, one k-half of W1
    __shared__ __align__(16) float xS[16 * 132];    // stride 132: aligned + conflict-free
    __shared__ float aSs[C1], aSd[C1];
    int tid = threadIdx.x;

    if (blockIdx.x < HIST_NB) {                     // ---- hist + rank: 4 edges/thread
        int e0 = blockIdx.x * 1024 + tid;
#pragma unroll
        for (int j = 0; j < 4; j++) {
            int e = e0 + j * 256;
            if (e < N_EDGES) {
                int d = e_dst[e];
                rank[e] = atomicAdd(&deg[d], 1);    // rank within dst bucket
            }
        }
        return;
    }

    // ---- gemm1: 16 nodes/block; thread t: node_l=t>>4, cols (t&15)*4..+3
    int node0 = (blockIdx.x - HIST_NB) * 16;
    for (int i = tid; i < (16 * IN_F) / 4; i += 256) {
        int r = i >> 5, c4 = (i & 31) << 2;          // 32 float4 per 128-wide row
        *(float4*)&xS[r * 132 + c4] = *(const float4*)&x[(node0 + r) * IN_F + c4];
    }
    if (tid < C1) { aSs[tid] = att_src1[tid]; aSd[tid] = att_dst1[tid]; }

    int node_l = tid >> 4;
    int cq = (tid & 15) << 2;
    const float* xrow = &xS[node_l * 132];
    float4 acc = {0.f, 0.f, 0.f, 0.f};
#pragma unroll
    for (int kt = 0; kt < 2; kt++) {                // two 64-wide k-tiles of W1
        __syncthreads();                            // protect wS reuse
        for (int i = tid; i < (64 * C1) / 4; i += 256)
            *(float4*)&wS[i * 4] = *(const float4*)&W1[kt * 64 * C1 + i * 4];
        __syncthreads();
        const float* xk = xrow + kt * 64;
#pragma unroll 4
        for (int k = 0; k < 64; k++) {
            float xv = xk[k];
            float4 wv = *(const float4*)&wS[k * C1 + cq];
            acc.x += xv * wv.x; acc.y += xv * wv.y; acc.z += xv * wv.z; acc.w += xv * wv.w;
        }
    }
    int node = node0 + node_l;
    *(float4*)&h1[node * C1 + cq] = acc;

    float ps = acc.x * aSs[cq] + acc.y * aSs[cq + 1] + acc.z * aSs[cq + 2] + acc.w * aSs[cq + 3];
    float pd = acc.x * aSd[cq] + acc.y * aSd[cq + 1] + acc.z * aSd[cq + 2] + acc.w * aSd[cq + 3];
    ps += __shfl_xor(ps, 1); ps += __shfl_xor(ps, 2);
    pd += __shfl_xor(pd, 1); pd += __shfl_xor(pd, 2);
    if ((tid & 3) == 0) {
        int h = (tid & 15) >> 2;
        a_src1[node * 4 + h] = ps;
        a_dst1[node * 4 + h] = pd;
    }
}

// pass 1: per-block sums of deg (1024 elems per 256-thread block)
__global__ __launch_bounds__(256) void k_scan1(const int* __restrict__ deg,
                                               int* __restrict__ partial) {
    __shared__ int wsum[4];
    int tid = threadIdx.x;
    int i0 = blockIdx.x * SCAN_TILE + tid * 4;
    int s = 0;
#pragma unroll
    for (int j = 0; j < 4; j++) { int i = i0 + j; if (i < N_NODES) s += deg[i]; }
    for (int off = 32; off; off >>= 1) s += __shfl_xor(s, off);
    if ((tid & 63) == 0) wsum[tid >> 6] = s;
    __syncthreads();
    if (tid == 0) partial[blockIdx.x] = wsum[0] + wsum[1] + wsum[2] + wsum[3];
}

// pass 2: exclusive scan of the 98 partials (single tiny block)
__global__ void k_scan2(const int* __restrict__ partial, int* __restrict__ pscan,
                        int* __restrict__ rowptr) {
    __shared__ int buf[128];
    int tid = threadIdx.x;
    int v = (tid < SCAN_NB) ? partial[tid] : 0;
    buf[tid] = v;
    __syncthreads();
    for (int d = 1; d < 128; d <<= 1) {
        int t = (tid >= d) ? buf[tid - d] : 0;
        __syncthreads();
        buf[tid] += t;
        __syncthreads();
    }
    if (tid < SCAN_NB) pscan[tid] = buf[tid] - v;    // exclusive
    if (tid == 0) rowptr[N_NODES] = N_EDGES;         // total is static
}

// pass 3: block-local exclusive scan + block offset -> rowptr
__global__ __launch_bounds__(256) void k_scan3(const int* __restrict__ deg,
                                               const int* __restrict__ pscan,
                                               int* __restrict__ rowptr) {
    __shared__ int wsum[4];
    int tid = threadIdx.x, lane = tid & 63, wave = tid >> 6;
    int i0 = blockIdx.x * SCAN_TILE + tid * 4;
    int v0 = 0, v1 = 0, v2 = 0, v3 = 0;
    if (i0 + 0 < N_NODES) v0 = deg[i0 + 0];
    if (i0 + 1 < N_NODES) v1 = deg[i0 + 1];
    if (i0 + 2 < N_NODES) v2 = deg[i0 + 2];
    if (i0 + 3 < N_NODES) v3 = deg[i0 + 3];
    int s0 = v0, s1 = s0 + v1, s2 = s1 + v2, s3 = s2 + v3;   // thread-local inclusive
    int t = s3;                                              // wave inclusive scan
    for (int off = 1; off < 64; off <<= 1) {
        int u = __shfl_up(t, off);
        if (lane >= off) t += u;
    }
    if (lane == 63) wsum[wave] = t;
    __syncthreads();
    int woff = 0;
    for (int w = 0; w < wave; w++) woff += wsum[w];
    int base = pscan[blockIdx.x] + woff + (t - s3);          // exclusive prefix
    if (i0 + 0 < N_NODES) rowptr[i0 + 0] = base;
    if (i0 + 1 < N_NODES) rowptr[i0 + 1] = base + s0;
    if (i0 + 2 < N_NODES) rowptr[i0 + 2] = base + s1;
    if (i0 + 3 < N_NODES) rowptr[i0 + 3] = base + s2;
}

// atomic-free scatter + layer1 edge-weight precompute in fp32 (fills the
// scatter's latency shadow with the exp/lrelu work agg1 used to do).
__global__ __launch_bounds__(256) void k_scatter(
    const int* __restrict__ e_src, const int* __restrict__ e_dst,
    const int* __restrict__ rank, const int* __restrict__ rowptr,
    const float* __restrict__ a_src1, const float* __restrict__ a_dst1,
    int* __restrict__ csr, float4* __restrict__ wcsr) {
    int e0 = blockIdx.x * 1024 + threadIdx.x;
#pragma unroll
    for (int j = 0; j < 4; j++) {
        int e = e0 + j * 256;
        if (e < N_EDGES) {
            int s = e_src[e], d = e_dst[e];
            int slot = rowptr[d] + rank[e];
            float4 as = *(const float4*)&a_src1[s * 4];
            float4 ad = *(const float4*)&a_dst1[d * 4];
            float4 wp;
            wp.x = __expf(lrelu(as.x + ad.x));
            wp.y = __expf(lrelu(as.y + ad.y));
            wp.z = __expf(lrelu(as.z + ad.z));
            wp.w = __expf(lrelu(as.w + ad.w));
            csr[slot] = s;
            wcsr[slot] = wp;
        }
    }
}

// ---------------- layer 1 aggregate (one wave per node) ---------------------
// weights precomputed in k_scatter (fp32); stage (src,w) to LDS from coalesced
// 20B/edge reads; serial loop: 2x ds_read_b128 + 4 fp32 gathers + 4 FMAs / 4 edges.
__global__ __launch_bounds__(256) void k_agg1(
    const float* __restrict__ h1, const float* __restrict__ a_src1,
    const float* __restrict__ a_dst1, const int* __restrict__ rowptr,
    const int* __restrict__ csr, const float4* __restrict__ wcsr,
    const float* __restrict__ b1, float* __restrict__ out_emb) {
    __shared__ __align__(16) int2 swS[4][4][66];   // [wave][head][edge]; 66 -> 16B-aligned heads
    int tid = threadIdx.x;
    int lane = tid & 63, wave = tid >> 6;
    int node = blockIdx.x * 4 + wave;
    int col = lane, h = lane >> 4;
    int rs = rowptr[node];
    int deg = rowptr[node + 1] - rs;

    float4 ad4 = *(const float4*)&a_dst1[node * 4];
    float4 as4 = *(const float4*)&a_src1[node * 4];
    float4 e04 = {lrelu(as4.x + ad4.x), lrelu(as4.y + ad4.y),
                  lrelu(as4.z + ad4.z), lrelu(as4.w + ad4.w)};
    float w0 = __expf(selh(e04, h));                // self-loop weight (no shift)
    float acc0 = w0 * h1[node * C1 + col];
    float acc1 = 0.f, acc2 = 0.f, acc3 = 0.f;
    float4 sac4 = {0.f, 0.f, 0.f, 0.f};            // lane-parallel denominator

    for (int base = 0; base < deg; base += 64) {
        int idx = base + lane;
        int s_l = 0;
        float4 w4 = {0.f, 0.f, 0.f, 0.f};
        if (idx < deg) {                            // coalesced 20B/edge stage
            s_l = csr[rs + idx];
            w4 = wcsr[rs + idx];
        }
        sac4.x += w4.x; sac4.y += w4.y; sac4.z += w4.z; sac4.w += w4.w;
        swS[wave][0][lane] = make_int2(s_l, __float_as_int(w4.x));
        swS[wave][1][lane] = make_int2(s_l, __float_as_int(w4.y));
        swS[wave][2][lane] = make_int2(s_l, __float_as_int(w4.z));
        swS[wave][3][lane] = make_int2(s_l, __float_as_int(w4.w));
        int nrem4 = (min(64, deg - base) + 3) & ~3; // pad slots carry w=0
        for (int j = 0; j < nrem4; j += 4) {        // 2x ds_read_b128, 4 chains
            int4 q0 = *(const int4*)&swS[wave][h][j];
            int4 q1 = *(const int4*)&swS[wave][h][j + 2];
            acc0 = fmaf(__int_as_float(q0.y), h1[q0.x * C1 + col], acc0);
            acc1 = fmaf(__int_as_float(q0.w), h1[q0.z * C1 + col], acc1);
            acc2 = fmaf(__int_as_float(q1.y), h1[q1.x * C1 + col], acc2);
            acc3 = fmaf(__int_as_float(q1.w), h1[q1.z * C1 + col], acc3);
        }
    }
    float acc = (acc0 + acc1) + (acc2 + acc3);
    for (int off = 32; off; off >>= 1) {            // reduce denominator (once)
        sac4.x += __shfl_xor(sac4.x, off);
        sac4.y += __shfl_xor(sac4.y, off);
        sac4.z += __shfl_xor(sac4.z, off);
        sac4.w += __shfl_xor(sac4.w, off);
    }
    float sacc = selh(sac4, h) + w0;

    float o = acc / sacc + b1[col];
    o = (o > 0.f) ? o : expm1f(o);                  // ELU
    out_emb[node * C1 + col] = o;                   // fp32 embeddings == h_act
}

// ---------------- layer 2 GEMM + attention dots ----------------
__global__ __launch_bounds__(256) void k_gemm2(
    const float* __restrict__ h_act, const float* __restrict__ W2,
    const float* __restrict__ att_src2, const float* __restrict__ att_dst2,
    float* __restrict__ h2, float* __restrict__ a_src2, float* __restrict__ a_dst2) {
    __shared__ float wS[C1 * NC];                 // 4 KB [k][c]
    __shared__ __align__(16) float hS[16 * 68];   // stride 68: aligned + conflict-free
    __shared__ float aS[NC], aD[NC];
    int tid = threadIdx.x;
    int node0 = blockIdx.x * 16;
    if (tid < (C1 * NC) / 4)
        *(float4*)&wS[tid * 4] = *(const float4*)&W2[tid * 4];
    {   // 16 rows x 64 cols of h_act, 256 float4s
        int r = tid >> 4, c4 = (tid & 15) << 2;
        *(float4*)&hS[r * 68 + c4] = *(const float4*)&h_act[(node0 + r) * C1 + c4];
    }
    if (tid < NC) { aS[tid] = att_src2[tid]; aD[tid] = att_dst2[tid]; }
    __syncthreads();

    int node_l = tid >> 4, c = tid & 15;
    const float* hr = &hS[node_l * 68];
    float acc = 0.f;
#pragma unroll 8
    for (int k = 0; k < C1; k++) acc += hr[k] * wS[k * NC + c];
    int node = node0 + node_l;
    h2[node * NC + c] = acc;

    float ps = acc * aS[c], pd = acc * aD[c];
    for (int off = 8; off; off >>= 1) { ps += __shfl_xor(ps, off); pd += __shfl_xor(pd, off); }
    if (c == 0) { a_src2[node] = ps; a_dst2[node] = pd; }
}

// ---------------- layer 2 softmax-aggregate + log_softmax (no max pass) -----
__global__ __launch_bounds__(256) void k_agg2(
    const float* __restrict__ h2, const float* __restrict__ a_src2,
    const float* __restrict__ a_dst2, const int* __restrict__ rowptr,
    const int* __restrict__ csr, const float* __restrict__ b2,
    float* __restrict__ out_lsm) {
    __shared__ int2 swS[4][64];                     // [wave][edge] = (src, w)
    int tid = threadIdx.x;
    int lane = tid & 63, wave = tid >> 6;
    int node = blockIdx.x * 4 + wave;
    int esub = lane >> 4, c = lane & 15;
    int rs = rowptr[node];
    int deg = rowptr[node + 1] - rs;

    float adst = a_dst2[node];
    float w0 = __expf(lrelu(a_src2[node] + adst));
    float sacc_l = 0.f;                             // lane-parallel denominator
    float accA = (esub == 0) ? w0 * h2[node * NC + c] : 0.f;
    float accB = 0.f;

    for (int base = 0; base < deg; base += 64) {
        int idx = base + lane;
        int s_l = 0; float w_l = 0.f;
        if (idx < deg) {                            // lane-parallel weight compute
            s_l = csr[rs + idx];
            w_l = __expf(lrelu(a_src2[s_l] + adst));
        }
        sacc_l += w_l;
        swS[wave][lane] = make_int2(s_l, __float_as_int(w_l));
        int nrem8 = (min(64, deg - base) + 7) & ~7; // pad slots carry w=0
        for (int j2 = 0; j2 < nrem8; j2 += 8) {     // 2 pairs x (4 edges x 16 cols)
            int2 p0 = swS[wave][j2 + esub];
            int2 p1 = swS[wave][j2 + 4 + esub];
            accA = fmaf(__int_as_float(p0.y), h2[p0.x * NC + c], accA);
            accB = fmaf(__int_as_float(p1.y), h2[p1.x * NC + c], accB);
        }
    }
    float acc = accA + accB;
    acc += __shfl_xor(acc, 16); acc += __shfl_xor(acc, 32);
    for (int off = 32; off; off >>= 1) sacc_l += __shfl_xor(sacc_l, off);
    float sacc = sacc_l + w0;

    float logit = acc / sacc + b2[c];
    float mxl = logit;
    for (int off = 8; off; off >>= 1) mxl = fmaxf(mxl, __shfl_xor(mxl, off));
    float ex = __expf(logit - mxl);
    float se = ex;
    for (int off = 8; off; off >>= 1) se += __shfl_xor(se, off);
    float lsm = (logit - mxl) - __logf(se);
    if (esub == 0) out_lsm[node * NC + c] = lsm;
}

extern "C" void kernel_launch(void* const* d_in, const int* in_sizes, int n_in,
                              void* d_out, int out_size, void* d_ws, size_t ws_size,
                              hipStream_t stream) {
    const float* x   = (const float*)d_in[0];
    const int* ei    = (const int*)d_in[1];   // [2,E]: src row then dst row
    const float* W1  = (const float*)d_in[2];
    const float* as1 = (const float*)d_in[3];
    const float* ad1 = (const float*)d_in[4];
    const float* b1  = (const float*)d_in[5];
    const float* W2  = (const float*)d_in[6];
    const float* as2 = (const float*)d_in[7];
    const float* ad2 = (const float*)d_in[8];
    const float* b2  = (const float*)d_in[9];
    float* out = (float*)d_out;               // [N*16 log_softmax][N*64 embeddings]
    float* out_lsm = out;
    float* out_emb = out + (size_t)N_NODES * NC;

    float* ws = (float*)d_ws;
    float* h1     = ws;                              // N*64 (25.6 MB)
    float* a_src1 = h1     + (size_t)N_NODES * C1;   // N*4
    float* a_dst1 = a_src1 + (size_t)N_NODES * 4;    // N*4
    float* h2     = a_dst1 + (size_t)N_NODES * 4;    // N*16
    float* a_src2 = h2     + (size_t)N_NODES * NC;   // N
    float* a_dst2 = a_src2 + (size_t)N_NODES;        // N
    int*   deg    = (int*)(a_dst2 + N_NODES);        // N
    int*   rowptr = deg + N_NODES;                   // N+1
    int*   csr    = rowptr + N_NODES + 1;            // E
    int*   rank   = csr + N_EDGES;                   // E
    int*   partial= rank + N_EDGES;                  // SCAN_NB
    int*   pscan  = partial + SCAN_NB;               // SCAN_NB
    float4* wcsr  = (float4*)(pscan + SCAN_NB + 2);  // E x 16B (25.6 MB)
    // total ws use: ~86 MB

    const int* e_src = ei;
    const int* e_dst = ei + N_EDGES;

    hipMemsetAsync(deg, 0, (size_t)N_NODES * sizeof(int), stream);

    k_hist_gemm1<<<HIST_NB + GEMM1_NB, 256, 0, stream>>>(
        e_dst, deg, rank, x, W1, as1, ad1, h1, a_src1, a_dst1);

    k_scan1<<<SCAN_NB, 256, 0, stream>>>(deg, partial);
    k_scan2<<<1, 128, 0, stream>>>(partial, pscan, rowptr);
    k_scan3<<<SCAN_NB, 256, 0, stream>>>(deg, pscan, rowptr);

    k_scatter<<<HIST_NB, 256, 0, stream>>>(e_src, e_dst, rank, rowptr,
                                           a_src1, a_dst1, csr, wcsr);

    k_agg1 <<<N_NODES / 4, 256, 0, stream>>>(h1, a_src1, a_dst1, rowptr, csr,
                                             wcsr, b1, out_emb);
    k_gemm2<<<N_NODES / 16, 256, 0, stream>>>(out_emb, W2, as2, ad2, h2, a_src2, a_dst2);
    k_agg2 <<<N_NODES / 4, 256, 0, stream>>>(h2, a_src2, a_dst2, rowptr, csr, b2, out_lsm);
}